// Round 12
// baseline (46.360 us; speedup 1.0000x reference)
//
#include <hip/hip_runtime.h>

#define NUM_SLICE 32

// Problem constants (fixed by setup_inputs)
constexpr int Bc = 8;
constexpr int Cc = 128;
constexpr int Nc = 65536;

// R11: R10's exclusive-ownership structure, CPB 2->1. Each block owns ONE
// full channel row (one 256KB pure-sequential stream), computes final maxima
// for its 32 outputs, plain-stores. Grid (128,8) = 1024 blocks x 1024 thr
// (2 resident/CU = 32 waves/CU, two uniform residency generations).
constexpr int CPB     = 1;     // channels per block (full row)
constexpr int THREADS = 1024;
constexpr int PTS_PER_ITER = THREADS * 4;      // 4096 points / iter (float4)
constexpr int NITER   = Nc / PTS_PER_ITER;     // 16
constexpr int ACC_LD  = 33;    // padded stride
constexpr int NREP    = 2;     // replicas by lane parity: halves same-addr passes

typedef float f32x4 __attribute__((ext_vector_type(4)));
typedef int   i32x4 __attribute__((ext_vector_type(4)));

__global__ __launch_bounds__(THREADS, 8) void slice_pool_kernel(
    const float* __restrict__ in,       // [B, C, N]
    const int*   __restrict__ idx,      // [B, N], values in [0, 32)
    unsigned int* __restrict__ out)     // [B, C, 32] as uint bits (all >= 0)
{
    __shared__ unsigned int acc[NREP][CPB * ACC_LD];

    const int t = threadIdx.x;
    if (t < NREP * CPB * ACC_LD) (&acc[0][0])[t] = 0u;
    __syncthreads();

    const int c  = blockIdx.x;              // 0..127 (channel)
    const int b  = blockIdx.y;              // 0..7
    const int rep = t & 1;                  // lane-parity replica

    const i32x4* __restrict__ idx4   = (const i32x4*)(idx + (size_t)b * Nc);
    const float* __restrict__ inbase = in + ((size_t)b * Cc + c) * Nc;

    unsigned int* __restrict__ accr = acc[rep];

    #pragma unroll 2
    for (int p = 0; p < NITER; ++p) {
        const int e    = p * THREADS + t;  // int4 slot within row
        const i32x4 iv = idx4[e];          // idx row: L2/L3-served re-reads
        const int off  = e * 4;            // element offset within row
        const f32x4 v = *(const f32x4*)(inbase + off);
        // fmax(x,0) == 0 bits iff x <= 0: those atomics are no-ops vs the
        // zero-initialized accumulator -> skip (halves active lanes).
        const unsigned int bx = __float_as_uint(fmaxf(v[0], 0.0f));
        const unsigned int by = __float_as_uint(fmaxf(v[1], 0.0f));
        const unsigned int bz = __float_as_uint(fmaxf(v[2], 0.0f));
        const unsigned int bw = __float_as_uint(fmaxf(v[3], 0.0f));
        if (bx) atomicMax(&accr[iv[0]], bx);
        if (by) atomicMax(&accr[iv[1]], by);
        if (bz) atomicMax(&accr[iv[2]], bz);
        if (bw) atomicMax(&accr[iv[3]], bw);
    }
    __syncthreads();

    // Epilogue: block exclusively owns its 32 outputs -> plain store
    // (unconditional: also overwrites harness poison; empty slice -> 0).
    if (t < NUM_SLICE) {
        unsigned int v = acc[0][t];
        const unsigned int v1 = acc[1][t];
        v = v > v1 ? v : v1;
        out[(((size_t)b * Cc) + c) * NUM_SLICE + t] = v;
    }
}

extern "C" void kernel_launch(void* const* d_in, const int* in_sizes, int n_in,
                              void* d_out, int out_size, void* d_ws, size_t ws_size,
                              hipStream_t stream) {
    const float* in  = (const float*)d_in[0];   // [8,128,65536,1] f32
    const int*   idx = (const int*)  d_in[1];   // [8,65536] i32
    unsigned int* out = (unsigned int*)d_out;   // [8,128,32,1] f32 (>=0 bits)

    dim3 grid(Cc / CPB, Bc);                    // (128, 8) = 1024 blocks
    slice_pool_kernel<<<grid, THREADS, 0, stream>>>(in, idx, out);
}

// Round 13
// 45.706 us; speedup vs baseline: 1.0143x; 1.0143x over previous
//
#include <hip/hip_runtime.h>

#define NUM_SLICE 32

// Problem constants (fixed by setup_inputs)
constexpr int Bc = 8;
constexpr int Cc = 128;
constexpr int Nc = 65536;

// FINAL (R10 config, best measured: 45.9us = 5.89 TB/s = 93.5% of 6.29 TB/s
// copy ceiling). Exclusive-ownership tiling: each block owns 2 channels x ALL
// 64K points (2 x 256KB pure-sequential streams), computes final maxima for
// its 64 outputs, plain-stores. No init kernel, no global atomics, ONE
// dispatch. Grid (64, 8) = 512 blocks x 1024 thr = 2 blocks/CU = 32 waves/CU.
//
// Key design facts established over R0-R11:
// - clamp-at-zero semantics allow uint-bit atomicMax (exact, order-indep)
// - zero-skip halves active atomic lanes; NREP=2 lane-parity replicas halve
//   same-address passes; beyond that LDS atomics are off the critical path
// - fewer/longer sequential streams per block dominate perf (DRAM locality):
//   128/16/8/4/2/1 streams -> 72.5/60.9/53.3/48.5/45.9/46.4 us; knee at 2
// - nontemporal loads HURT (measured clean, R6); idx re-reads are L2-served
constexpr int CPB     = 2;     // channels per block (full rows)
constexpr int THREADS = 1024;
constexpr int PTS_PER_ITER = THREADS * 4;      // 4096 points / iter (float4)
constexpr int NITER   = Nc / PTS_PER_ITER;     // 16
constexpr int ACC_LD  = 33;    // padded stride: bank(c*33+s) = (c+s)%32
constexpr int NREP    = 2;     // replicas by lane parity: halves same-addr passes

typedef float f32x4 __attribute__((ext_vector_type(4)));
typedef int   i32x4 __attribute__((ext_vector_type(4)));

__global__ __launch_bounds__(THREADS, 8) void slice_pool_kernel(
    const float* __restrict__ in,       // [B, C, N]
    const int*   __restrict__ idx,      // [B, N], values in [0, 32)
    unsigned int* __restrict__ out)     // [B, C, 32] as uint bits (all >= 0)
{
    __shared__ unsigned int acc[NREP][CPB * ACC_LD];

    const int t = threadIdx.x;
    if (t < NREP * CPB * ACC_LD) (&acc[0][0])[t] = 0u;
    __syncthreads();

    const int cg = blockIdx.x;              // 0..63
    const int b  = blockIdx.y;              // 0..7
    const int c0 = cg * CPB;
    const int rep = t & 1;                  // lane-parity replica

    const i32x4* __restrict__ idx4   = (const i32x4*)(idx + (size_t)b * Nc);
    const float* __restrict__ inbase = in + ((size_t)b * Cc + c0) * Nc;

    unsigned int* __restrict__ accr = acc[rep];

    #pragma unroll 2
    for (int p = 0; p < NITER; ++p) {
        const int e    = p * THREADS + t;  // int4 slot within row
        const i32x4 iv = idx4[e];          // idx row: L2/L3-served re-reads
        const int off  = e * 4;            // element offset within row
        #pragma unroll
        for (int c = 0; c < CPB; ++c) {
            const f32x4 v = *(const f32x4*)(inbase + (size_t)c * Nc + off);
            const int base = c * ACC_LD;
            // fmax(x,0) == 0 bits iff x <= 0: those atomics are no-ops vs the
            // zero-initialized accumulator -> skip (halves active lanes).
            const unsigned int bx = __float_as_uint(fmaxf(v[0], 0.0f));
            const unsigned int by = __float_as_uint(fmaxf(v[1], 0.0f));
            const unsigned int bz = __float_as_uint(fmaxf(v[2], 0.0f));
            const unsigned int bw = __float_as_uint(fmaxf(v[3], 0.0f));
            if (bx) atomicMax(&accr[base + iv[0]], bx);
            if (by) atomicMax(&accr[base + iv[1]], by);
            if (bz) atomicMax(&accr[base + iv[2]], bz);
            if (bw) atomicMax(&accr[base + iv[3]], bw);
        }
    }
    __syncthreads();

    // Epilogue: block exclusively owns its 64 outputs -> plain store
    // (unconditional: also overwrites harness poison; empty slice -> 0).
    if (t < CPB * NUM_SLICE) {
        const int c = t >> 5;
        const int s = t & 31;
        unsigned int v = acc[0][c * ACC_LD + s];
        const unsigned int v1 = acc[1][c * ACC_LD + s];
        v = v > v1 ? v : v1;
        out[(((size_t)b * Cc) + c0 + c) * NUM_SLICE + s] = v;
    }
}

extern "C" void kernel_launch(void* const* d_in, const int* in_sizes, int n_in,
                              void* d_out, int out_size, void* d_ws, size_t ws_size,
                              hipStream_t stream) {
    const float* in  = (const float*)d_in[0];   // [8,128,65536,1] f32
    const int*   idx = (const int*)  d_in[1];   // [8,65536] i32
    unsigned int* out = (unsigned int*)d_out;   // [8,128,32,1] f32 (>=0 bits)

    dim3 grid(Cc / CPB, Bc);                    // (64, 8) = 512 blocks
    slice_pool_kernel<<<grid, THREADS, 0, stream>>>(in, idx, out);
}